// Round 15
// baseline (702.745 us; speedup 1.0000x reference)
//
#include <hip/hip_runtime.h>
#include <stdint.h>

#define NN 100000
#define NE 1600000
#define DD 128
#define NG 128
#define NPX 12500     // nodes per XCD partition (8 * 12500 = 100000)
#define NBS 25        // scan blocks: 25 * 4096 > NN+1

using f32x4  = __attribute__((ext_vector_type(4))) float;
using bf16x8 = __attribute__((ext_vector_type(8))) __bf16;

__device__ __forceinline__ unsigned short f2bf(float f) {
  unsigned int u = __builtin_bit_cast(unsigned int, f);
  u = (u + 0x7FFFu + ((u >> 16) & 1u)) >> 16;
  return (unsigned short)u;
}

__device__ __forceinline__ float2 bfu(unsigned int u) {
  float2 r;
  r.x = __builtin_bit_cast(float, u << 16);
  r.y = __builtin_bit_cast(float, u & 0xffff0000u);
  return r;
}

union ABu { uint4 q; bf16x8 v; };

// ---------------- CSR build (XCD-partitioned scatter) ----------------
__global__ void k_count(const int* __restrict__ dst, int* __restrict__ deg) {
  int xcd = blockIdx.x & 7;
  int e = (blockIdx.x >> 3) * 256 + threadIdx.x;
  if (e >= NE) return;
  int d = dst[e];
  if ((unsigned)(d - xcd * NPX) < (unsigned)NPX) atomicAdd(&deg[d], 1);
}

// ---- 3-kernel scan: rowptr = exclusive_scan(deg), rowptr[NN] = total ----
__global__ __launch_bounds__(1024) void k_scanA(const int* __restrict__ deg,
                                                int* __restrict__ rowptr,
                                                int* __restrict__ bsum) {
  __shared__ int wsum[16];
  const int tid = threadIdx.x, wid = tid >> 6, lane = tid & 63;
  int idx = blockIdx.x * 4096 + tid * 4;
  int v0 = (idx + 0 < NN) ? deg[idx + 0] : 0;
  int v1 = (idx + 1 < NN) ? deg[idx + 1] : 0;
  int v2 = (idx + 2 < NN) ? deg[idx + 2] : 0;
  int v3 = (idx + 3 < NN) ? deg[idx + 3] : 0;
  int tsum = v0 + v1 + v2 + v3;
  int sc = tsum;
  #pragma unroll
  for (int off = 1; off < 64; off <<= 1) {
    int n = __shfl_up(sc, off);
    if (lane >= off) sc += n;
  }
  if (lane == 63) wsum[wid] = sc;
  __syncthreads();
  if (wid == 0 && lane < 16) {
    int w = wsum[lane];
    #pragma unroll
    for (int off = 1; off < 16; off <<= 1) {
      int n = __shfl_up(w, off);
      if (lane >= off) w += n;
    }
    wsum[lane] = w;
  }
  __syncthreads();
  int excl = (wid ? wsum[wid - 1] : 0) + sc - tsum;
  if (idx     <= NN) rowptr[idx]     = excl;
  if (idx + 1 <= NN) rowptr[idx + 1] = excl + v0;
  if (idx + 2 <= NN) rowptr[idx + 2] = excl + v0 + v1;
  if (idx + 3 <= NN) rowptr[idx + 3] = excl + v0 + v1 + v2;
  if (tid == 1023) bsum[blockIdx.x] = wsum[15];   // block total
}

__global__ void k_scanB(int* __restrict__ bsum) {
  int lane = threadIdx.x & 63;
  int v = (lane < NBS) ? bsum[lane] : 0;
  int sc = v;
  #pragma unroll
  for (int off = 1; off < 64; off <<= 1) {
    int n = __shfl_up(sc, off);
    if (lane >= off) sc += n;
  }
  if (lane < NBS) bsum[lane] = sc - v;   // exclusive
}

__global__ __launch_bounds__(1024) void k_scanC(int* __restrict__ rowptr,
                                                const int* __restrict__ bsum) {
  int add = bsum[blockIdx.x];
  int idx = blockIdx.x * 4096 + threadIdx.x * 4;
  if (idx     <= NN) rowptr[idx]     += add;
  if (idx + 1 <= NN) rowptr[idx + 1] += add;
  if (idx + 2 <= NN) rowptr[idx + 2] += add;
  if (idx + 3 <= NN) rowptr[idx + 3] += add;
}

__global__ void k_fill(const int* __restrict__ src, const int* __restrict__ dst,
                       const int* __restrict__ rowptr, int* __restrict__ cursor,
                       int* __restrict__ csr) {
  int xcd = blockIdx.x & 7;
  int e = (blockIdx.x >> 3) * 256 + threadIdx.x;
  if (e >= NE) return;
  int d = dst[e];
  if ((unsigned)(d - xcd * NPX) < (unsigned)NPX) {
    int pos = rowptr[d] + atomicAdd(&cursor[d], 1);
    csr[pos] = src[e];
  }
}

// ---------------- weight transpose + bf16 convert ----------------
__global__ void k_wconv(const float* __restrict__ w0, const float* __restrict__ w1,
                        const float* __restrict__ w2, const float* __restrict__ w3,
                        const float* __restrict__ w4, const float* __restrict__ w5,
                        unsigned short* __restrict__ wt) {
  int idx = blockIdx.x * 256 + threadIdx.x;
  if (idx >= 6 * 16384) return;
  int m = idx >> 14, rem = idx & 16383;
  int n = rem >> 7, k = rem & 127;
  const float* W = (m == 0) ? w0 : (m == 1) ? w1 : (m == 2) ? w2
                 : (m == 3) ? w3 : (m == 4) ? w4 : w5;
  wt[idx] = f2bf(W[k * 128 + n]);   // wt[m][n][k] = W[k][n]
}

// ---------------- x -> bf16 ----------------
__global__ void k_xconv(const float* __restrict__ x, unsigned short* __restrict__ xb) {
  int i = blockIdx.x * 256 + threadIdx.x;
  if (i >= NN * DD / 4) return;
  float4 v = ((const float4*)x)[i];
  uint2 p;
  p.x = (unsigned int)f2bf(v.x) | ((unsigned int)f2bf(v.y) << 16);
  p.y = (unsigned int)f2bf(v.z) | ((unsigned int)f2bf(v.w) << 16);
  ((uint2*)xb)[i] = p;
}

// ---------------- fused GIN layer: aggregate + MLP ----------------
// 6250 blocks x 1024 threads (16 waves) per 16 nodes -> 100000 gather waves,
// ZERO intra-wave divergence: wave wv gathers node blockBase+wv as a full
// 256B row (lane = one uint = 2 bf16), 8 rows in flight (R8's proven loop;
// j/je wave-uniform -> csr reads become scalar loads). Result -> XOR-swizzled
// LDS tile [16][128] (16B chunk c of row r at c ^ (r&7)).
// MFMA: waves 0..7 each own one n-block: GEMM1 -> barrier -> u overwrites
// tile -> barrier -> GEMM2 -> bf16 store. Waves 8..15 idle through the short
// MFMA tail (other blocks fill the CU).
__global__ __launch_bounds__(1024) void k_gin(const unsigned short* __restrict__ hb,
                                              const int* __restrict__ rowptr,
                                              const int* __restrict__ csr,
                                              const unsigned short* __restrict__ w1t,
                                              const float* __restrict__ b1,
                                              const unsigned short* __restrict__ w2t,
                                              const float* __restrict__ b2,
                                              unsigned short* __restrict__ hout) {
  __shared__ unsigned short tile[16 * DD];   // 4 KB
  const int wv   = threadIdx.x >> 6;   // 0..15
  const int lane = threadIdx.x & 63;
  const int blockBase = blockIdx.x * 16;
  const unsigned int* h32 = (const unsigned int*)hb;
  unsigned int* t32 = (unsigned int*)tile;

  // ---- phase 1: wave wv gathers node blockBase+wv (full row, no divergence) ----
  {
    const int node = blockBase + wv;     // NN = 6250*16 exactly
    float2 acc = bfu(h32[(size_t)node * 64 + lane]);   // self
    int j = rowptr[node];
    const int je = rowptr[node + 1];
    for (; j + 7 < je; j += 8) {
      int s0 = csr[j],     s1 = csr[j + 1], s2 = csr[j + 2], s3 = csr[j + 3];
      int s4 = csr[j + 4], s5 = csr[j + 5], s6 = csr[j + 6], s7 = csr[j + 7];
      unsigned int v0 = h32[(size_t)s0 * 64 + lane];
      unsigned int v1 = h32[(size_t)s1 * 64 + lane];
      unsigned int v2 = h32[(size_t)s2 * 64 + lane];
      unsigned int v3 = h32[(size_t)s3 * 64 + lane];
      unsigned int v4 = h32[(size_t)s4 * 64 + lane];
      unsigned int v5 = h32[(size_t)s5 * 64 + lane];
      unsigned int v6 = h32[(size_t)s6 * 64 + lane];
      unsigned int v7 = h32[(size_t)s7 * 64 + lane];
      float2 a0 = bfu(v0), a1 = bfu(v1), a2 = bfu(v2), a3 = bfu(v3);
      float2 a4 = bfu(v4), a5 = bfu(v5), a6 = bfu(v6), a7 = bfu(v7);
      acc.x += ((a0.x + a1.x) + (a2.x + a3.x)) + ((a4.x + a5.x) + (a6.x + a7.x));
      acc.y += ((a0.y + a1.y) + (a2.y + a3.y)) + ((a4.y + a5.y) + (a6.y + a7.y));
    }
    for (; j < je; ++j) {
      float2 a = bfu(h32[(size_t)csr[j] * 64 + lane]);
      acc.x += a.x; acc.y += a.y;
    }
    unsigned int packed = (unsigned int)f2bf(acc.x) | ((unsigned int)f2bf(acc.y) << 16);
    int c = lane >> 2;                  // 16B chunk index 0..15
    int o = lane & 3;                   // uint within chunk
    t32[wv * 64 + ((c ^ (wv & 7)) << 2) + o] = packed;
  }
  __syncthreads();

  // ---- phase 2: waves 0..7 run the MLP, n-block = wv ----
  const int r16 = lane & 15;
  const int kg  = lane >> 4;
  f32x4 acc1 = (f32x4){0.f, 0.f, 0.f, 0.f};
  if (wv < 8) {
    #pragma unroll
    for (int s = 0; s < 4; ++s) {
      ABu au;
      au.q = *(const uint4*)(tile + r16 * DD + ((((s << 2) + kg) ^ (r16 & 7)) << 3));
      ABu bu; bu.q = *(const uint4*)(w1t + (wv * 16 + r16) * DD + s * 32 + kg * 8);
      acc1 = __builtin_amdgcn_mfma_f32_16x16x32_bf16(au.v, bu.v, acc1, 0, 0, 0);
    }
  }
  __syncthreads();   // all A reads done before u overwrites the tile
  if (wv < 8) {
    int n = wv * 16 + r16;
    float bias = b1[n];
    #pragma unroll
    for (int reg = 0; reg < 4; ++reg) {
      int urow = (kg << 2) + reg;
      float v = acc1[reg] + bias;
      v = v > 0.f ? v : 0.f;
      tile[urow * DD + ((((n >> 3) ^ (urow & 7)) << 3) | (n & 7))] = f2bf(v);
    }
  }
  __syncthreads();
  if (wv < 8) {
    f32x4 acc2 = (f32x4){0.f, 0.f, 0.f, 0.f};
    #pragma unroll
    for (int s = 0; s < 4; ++s) {
      ABu au;
      au.q = *(const uint4*)(tile + r16 * DD + ((((s << 2) + kg) ^ (r16 & 7)) << 3));
      ABu bu; bu.q = *(const uint4*)(w2t + (wv * 16 + r16) * DD + s * 32 + kg * 8);
      acc2 = __builtin_amdgcn_mfma_f32_16x16x32_bf16(au.v, bu.v, acc2, 0, 0, 0);
    }
    int n = wv * 16 + r16;
    float bias = b2[n];
    #pragma unroll
    for (int reg = 0; reg < 4; ++reg) {
      int row = blockBase + (kg << 2) + reg;
      hout[row * DD + n] = f2bf(acc2[reg] + bias);
    }
  }
}

// ---------------- fused pooling: one block per graph (batch sorted) ----------------
__global__ __launch_bounds__(256) void k_pool(const unsigned short* __restrict__ hb,
                                              const int* __restrict__ batch,
                                              float* __restrict__ out) {
  const int g  = blockIdx.x;
  const int f2 = threadIdx.x & 63;
  const int rp = threadIdx.x >> 6;
  int lo = 0, hi = NN;
  while (lo < hi) { int m = (lo + hi) >> 1; if (batch[m] < g) lo = m + 1; else hi = m; }
  const int start = lo;
  hi = NN;
  while (lo < hi) { int m = (lo + hi) >> 1; if (batch[m] < g + 1) lo = m + 1; else hi = m; }
  const int end = lo;

  const unsigned int* h32 = (const unsigned int*)hb;
  float2 acc = {0.f, 0.f};
  int i = start + rp;
  for (; i + 4 < end; i += 8) {
    float2 a = bfu(h32[(size_t)i * 64 + f2]);
    float2 b = bfu(h32[(size_t)(i + 4) * 64 + f2]);
    acc.x += a.x + b.x; acc.y += a.y + b.y;
  }
  for (; i < end; i += 4) {
    float2 a = bfu(h32[(size_t)i * 64 + f2]);
    acc.x += a.x; acc.y += a.y;
  }

  __shared__ float2 part[4][64];
  part[rp][f2] = acc;
  __syncthreads();
  if (rp == 0) {
    float2 t0 = part[0][f2], t1 = part[1][f2], t2 = part[2][f2], t3 = part[3][f2];
    float inv = 1.0f / (float)max(end - start, 1);
    out[g * DD + 2 * f2]     = (t0.x + t1.x + t2.x + t3.x) * inv;
    out[g * DD + 2 * f2 + 1] = (t0.y + t1.y + t2.y + t3.y) * inv;
  }
}

// ---------------- launch ----------------
extern "C" void kernel_launch(void* const* d_in, const int* in_sizes, int n_in,
                              void* d_out, int out_size, void* d_ws, size_t ws_size,
                              hipStream_t stream) {
  const float* x    = (const float*)d_in[0];
  const int* ei     = (const int*)d_in[1];
  const int* src    = ei;
  const int* dst    = ei + NE;
  const int* batch  = (const int*)d_in[2];

  char* ws = (char*)d_ws;
  size_t off = 0;
  auto alloc = [&](size_t bytes) { char* p = ws + off; off = (off + bytes + 255) & ~(size_t)255; return p; };

  int*  deg    = (int*)alloc(2 * NN * 4);       // deg + cursor contiguous
  int*  cursor = deg + NN;
  int*  rowptr = (int*)alloc((NN + 1) * 4);
  int*  bsum   = (int*)alloc(NBS * 4);
  int*  csr    = (int*)alloc(NE * 4);
  unsigned short* wt = (unsigned short*)alloc(6 * 16384 * 2);
  unsigned short* xb = (unsigned short*)alloc((size_t)NN * DD * 2);
  unsigned short* hA = (unsigned short*)alloc((size_t)NN * DD * 2);
  unsigned short* hB = (unsigned short*)alloc((size_t)NN * DD * 2);

  hipMemsetAsync(deg, 0, 2 * NN * 4, stream);

  k_wconv<<<(6 * 16384 + 255) / 256, 256, 0, stream>>>(
      (const float*)d_in[3], (const float*)d_in[5],
      (const float*)d_in[7], (const float*)d_in[9],
      (const float*)d_in[11], (const float*)d_in[13], wt);
  k_xconv<<<(NN * DD / 4 + 255) / 256, 256, 0, stream>>>(x, xb);

  const int echunks = (NE + 255) / 256;
  k_count<<<8 * echunks, 256, 0, stream>>>(dst, deg);
  k_scanA<<<NBS, 1024, 0, stream>>>(deg, rowptr, bsum);
  k_scanB<<<1, 64, 0, stream>>>(bsum);
  k_scanC<<<NBS, 1024, 0, stream>>>(rowptr, bsum);
  k_fill<<<8 * echunks, 256, 0, stream>>>(src, dst, rowptr, cursor, csr);

  const unsigned short* hin = xb;
  unsigned short* houts[3] = {hA, hB, hA};
  for (int l = 0; l < 3; ++l) {
    k_gin<<<NN / 16, 1024, 0, stream>>>(
        hin, rowptr, csr,
        wt + (2 * l) * 16384, (const float*)d_in[4 + 4 * l],
        wt + (2 * l + 1) * 16384, (const float*)d_in[6 + 4 * l], houts[l]);
    hin = houts[l];
  }

  k_pool<<<NG, 256, 0, stream>>>(hin, batch, (float*)d_out);
}